// Round 6
// baseline (507.718 us; speedup 1.0000x reference)
//
#include <hip/hip_runtime.h>

#define N_NODES 100000
#define N_EDGES 1200000
#define LAYERS 4
#define SLOPE 0.01f

#define NPAIR (N_NODES / 2)                 // 50000 (N even)

// two-level zero-atomic counting sort
#define BUCKET_SHIFT 7
#define NB2 ((N_NODES + 127) >> 7)          // 782 buckets of 128 nodes
#define NBLK 128                            // scatter blocks
#define EPB (N_EDGES / NBLK)                // 9375 (exact)

__device__ __forceinline__ float leaky(float v) { return v >= 0.f ? v : SLOPE * v; }

#define ACC16(h, v, a, b, c, d) \
    h[0]  += v * a.x; h[1]  += v * a.y; h[2]  += v * a.z; h[3]  += v * a.w; \
    h[4]  += v * b.x; h[5]  += v * b.y; h[6]  += v * b.z; h[7]  += v * b.w; \
    h[8]  += v * c.x; h[9]  += v * c.y; h[10] += v * c.z; h[11] += v * c.w; \
    h[12] += v * d.x; h[13] += v * d.y; h[14] += v * d.z; h[15] += v * d.w;

#define ACC8(r, v, a, b) \
    r[0] += v * a.x; r[1] += v * a.y; r[2] += v * a.z; r[3] += v * a.w; \
    r[4] += v * b.x; r[5] += v * b.y; r[6] += v * b.z; r[7] += v * b.w;

// ---------------------------------------------------------------------------
// CSR build — zero global atomics (round-4 form, verified).
// ---------------------------------------------------------------------------
__global__ __launch_bounds__(256) void hist_k(
    const int* __restrict__ dst, int* __restrict__ Hg)
{
    __shared__ int lh[NB2];
    for (int i = threadIdx.x; i < NB2; i += 256) lh[i] = 0;
    __syncthreads();
    int blk = blockIdx.x;
    int e1 = blk * EPB + EPB;
    for (int e = blk * EPB + threadIdx.x; e < e1; e += 256)
        atomicAdd(&lh[dst[e] >> BUCKET_SHIFT], 1);
    __syncthreads();
    for (int i = threadIdx.x; i < NB2; i += 256) Hg[blk * NB2 + i] = lh[i];
}

__global__ __launch_bounds__(NBLK) void scan_blocks_k(
    int* __restrict__ Hg, int* __restrict__ T)
{
    __shared__ int s[NBLK];
    int b = blockIdx.x, t = threadIdx.x;
    int v = Hg[t * NB2 + b];
    s[t] = v; __syncthreads();
    for (int off = 1; off < NBLK; off <<= 1) {
        int y = (t >= off) ? s[t - off] : 0;
        __syncthreads();
        s[t] += y;
        __syncthreads();
    }
    Hg[t * NB2 + b] = s[t] - v;
    if (t == NBLK - 1) T[b] = s[t];
}

__global__ __launch_bounds__(256) void scan_T_k(
    const int* __restrict__ T, int* __restrict__ BS)
{
    __shared__ int s[256];
    int t = threadIdx.x;
    int beg = t * 4, end = beg + 4 > NB2 ? NB2 : beg + 4;
    int v[4]; int sum = 0;
    for (int i = beg, u = 0; i < end; i++, u++) { v[u] = sum; sum += T[i]; }
    s[t] = sum; __syncthreads();
    for (int off = 1; off < 256; off <<= 1) {
        int y = (t >= off) ? s[t - off] : 0;
        __syncthreads();
        s[t] += y;
        __syncthreads();
    }
    int excl = s[t] - sum;
    for (int i = beg, u = 0; i < end; i++, u++) BS[i] = excl + v[u];
    if (t == 0) BS[NB2] = N_EDGES;
}

__global__ __launch_bounds__(256) void scatter_k(
    const int* __restrict__ src, const int* __restrict__ dst,
    const float* __restrict__ w, const int* __restrict__ Hg,
    const int* __restrict__ BS, int2* __restrict__ sE)
{
    __shared__ int cur[NB2];
    int blk = blockIdx.x;
    for (int i = threadIdx.x; i < NB2; i += 256)
        cur[i] = BS[i] + Hg[blk * NB2 + i];
    __syncthreads();
    int e1 = blk * EPB + EPB;
    for (int e = blk * EPB + threadIdx.x; e < e1; e += 256) {
        int d = dst[e];
        int p = atomicAdd(&cur[d >> BUCKET_SHIFT], 1);
        sE[p] = make_int2(src[e] | ((d & 127) << 17), __float_as_int(w[e]));
    }
}

__global__ __launch_bounds__(256) void finalize_k(
    const int* __restrict__ BS, const int2* __restrict__ sE,
    int* __restrict__ offs, int2* __restrict__ ep)
{
    __shared__ int cnt[128];
    __shared__ int s[128];
    __shared__ int cur[128];
    int b = blockIdx.x, t = threadIdx.x;
    int s0 = BS[b], s1 = BS[b + 1];
    if (t < 128) cnt[t] = 0;
    __syncthreads();
    for (int i = s0 + t; i < s1; i += 256)
        atomicAdd(&cnt[(sE[i].x >> 17) & 127], 1);
    __syncthreads();
    int v = 0;
    if (t < 128) { v = cnt[t]; s[t] = v; }
    __syncthreads();
    for (int off = 1; off < 128; off <<= 1) {
        int y = (t >= off && t < 128) ? s[t - off] : 0;
        __syncthreads();
        if (t < 128) s[t] += y;
        __syncthreads();
    }
    if (t < 128) {
        int excl = s[t] - v;
        cur[t] = s0 + excl;
        int node = b * 128 + t;
        if (node < N_NODES) offs[node] = s0 + excl;
    }
    if (b == NB2 - 1 && t == 0) offs[N_NODES] = N_EDGES;
    __syncthreads();
    for (int i = s0 + t; i < s1; i += 256) {
        int2 e = sE[i];
        int p = atomicAdd(&cur[(e.x >> 17) & 127], 1);
        ep[p] = make_int2(e.x & 0x1FFFF, e.y);
    }
}

// ---------------------------------------------------------------------------
// Kernel A: encoder + LN(layer0) + dual GEMM(layer0).
// 4 lanes x 2 nodes per thread, stage-1 fused.  LDS diet: nodeW/edgeW read
// straight from global (16KB block-uniform working set -> L1-resident);
// LDS 58.9 -> 42.4 KB => 3 blocks/CU (12 waves) instead of 2.
// ---------------------------------------------------------------------------
__global__ __launch_bounds__(256) void enc_ln_gemm(
    const float* __restrict__ x,
    const float* __restrict__ W1, const float* __restrict__ b1,
    const float* __restrict__ W2, const float* __restrict__ b2,
    const float* __restrict__ ln_g, const float* __restrict__ ln_b,
    const float* __restrict__ nodeW, const float* __restrict__ node_b,
    const float* __restrict__ edgeW, const float* __restrict__ edge_b,
    float* __restrict__ H, float* __restrict__ Y, float* __restrict__ Z)
{
    __shared__ float sW1t[128 * 16];   // [k][i] = W1[i][k]
    __shared__ float sW2[128 * 64];
    __shared__ float sb1[128];
    __shared__ float sb2[64];
    __shared__ float sg[64], sb[64], sby[32];
    for (int idx = threadIdx.x; idx < 16 * 128; idx += 256) {
        int i = idx / 128, k = idx % 128;
        sW1t[k * 16 + i] = W1[idx];
    }
    for (int idx = threadIdx.x; idx < 128 * 64; idx += 256) sW2[idx] = W2[idx];
    if (threadIdx.x < 128) sb1[threadIdx.x] = b1[threadIdx.x];
    if (threadIdx.x < 64) {
        sb2[threadIdx.x] = b2[threadIdx.x];
        sg[threadIdx.x] = ln_g[threadIdx.x];
        sb[threadIdx.x] = ln_b[threadIdx.x];
    }
    if (threadIdx.x < 32) sby[threadIdx.x] = node_b[threadIdx.x] + edge_b[threadIdx.x];
    __syncthreads();

    int base = blockIdx.x * 256 + threadIdx.x;
    int pair = base >> 2;
    int q = base & 3;
    if (pair >= NPAIR) return;
    int n0 = pair * 2, n1 = n0 + 1;

    float xi0[16], xi1[16];
    {
        const float4* xv0 = (const float4*)(x + (size_t)n0 * 16);
        const float4* xv1 = (const float4*)(x + (size_t)n1 * 16);
        #pragma unroll
        for (int i = 0; i < 4; i++) {
            float4 t = xv0[i];
            xi0[4 * i] = t.x; xi0[4 * i + 1] = t.y; xi0[4 * i + 2] = t.z; xi0[4 * i + 3] = t.w;
            float4 u = xv1[i];
            xi1[4 * i] = u.x; xi1[4 * i + 1] = u.y; xi1[4 * i + 2] = u.z; xi1[4 * i + 3] = u.w;
        }
    }

    // fused stage 1 + stage 2, both nodes share every weight read
    float h0[16], h1[16];
    #pragma unroll
    for (int jj = 0; jj < 16; jj++) { h0[jj] = sb2[q * 16 + jj]; h1[jj] = h0[jj]; }
    #pragma unroll 4
    for (int kk = 0; kk < 32; kk++) {
        int t = kk * 4 + q;
        const float4* wv = (const float4*)(sW1t + t * 16);
        float4 w0 = wv[0], w1 = wv[1], w2 = wv[2], w3 = wv[3];
        float a0 = sb1[t];
        a0 += xi0[0] * w0.x + xi0[1] * w0.y + xi0[2] * w0.z + xi0[3] * w0.w;
        a0 += xi0[4] * w1.x + xi0[5] * w1.y + xi0[6] * w1.z + xi0[7] * w1.w;
        a0 += xi0[8] * w2.x + xi0[9] * w2.y + xi0[10] * w2.z + xi0[11] * w2.w;
        a0 += xi0[12] * w3.x + xi0[13] * w3.y + xi0[14] * w3.z + xi0[15] * w3.w;
        float a1 = sb1[t];
        a1 += xi1[0] * w0.x + xi1[1] * w0.y + xi1[2] * w0.z + xi1[3] * w0.w;
        a1 += xi1[4] * w1.x + xi1[5] * w1.y + xi1[6] * w1.z + xi1[7] * w1.w;
        a1 += xi1[8] * w2.x + xi1[9] * w2.y + xi1[10] * w2.z + xi1[11] * w2.w;
        a1 += xi1[12] * w3.x + xi1[13] * w3.y + xi1[14] * w3.z + xi1[15] * w3.w;
        float hv0 = leaky(a0);
        float hv1 = leaky(a1);
        #pragma unroll
        for (int ss = 0; ss < 4; ss++) {
            float v0 = __shfl(hv0, ss, 4);
            float v1 = __shfl(hv1, ss, 4);
            const float4* w = (const float4*)(sW2 + (kk * 4 + ss) * 64 + q * 16);
            float4 aa = w[0], bb = w[1], cc = w[2], dd = w[3];
            ACC16(h0, v0, aa, bb, cc, dd)
            ACC16(h1, v1, aa, bb, cc, dd)
        }
    }

    // LN over quad (both nodes)
    float s0 = 0.f, e0 = 0.f, s1 = 0.f, e1 = 0.f;
    #pragma unroll
    for (int jj = 0; jj < 16; jj++) {
        s0 += h0[jj]; e0 += h0[jj] * h0[jj];
        s1 += h1[jj]; e1 += h1[jj] * h1[jj];
    }
    s0 += __shfl_xor(s0, 1, 4); s0 += __shfl_xor(s0, 2, 4);
    e0 += __shfl_xor(e0, 1, 4); e0 += __shfl_xor(e0, 2, 4);
    s1 += __shfl_xor(s1, 1, 4); s1 += __shfl_xor(s1, 2, 4);
    e1 += __shfl_xor(e1, 1, 4); e1 += __shfl_xor(e1, 2, 4);
    float mu0 = s0 * (1.f / 64.f);
    float va0 = e0 * (1.f / 64.f) - mu0 * mu0;
    float r0  = rsqrtf(va0 + 1e-5f);
    float mu1 = s1 * (1.f / 64.f);
    float va1 = e1 * (1.f / 64.f) - mu1 * mu1;
    float r1  = rsqrtf(va1 + 1e-5f);

    #pragma unroll
    for (int jj = 0; jj < 16; jj++) {
        float g = sg[q * 16 + jj], bb = sb[q * 16 + jj];
        h0[jj] = (h0[jj] - mu0) * r0 * g + bb;   // hn in place
        h1[jj] = (h1[jj] - mu1) * r1 * g + bb;
    }
    {
        float4* hs0 = (float4*)(H + (size_t)n0 * 64 + q * 16);
        float4* hs1 = (float4*)(H + (size_t)n1 * 64 + q * 16);
        #pragma unroll
        for (int c = 0; c < 4; c++) {
            hs0[c] = make_float4(h0[4 * c], h0[4 * c + 1], h0[4 * c + 2], h0[4 * c + 3]);
            hs1[c] = make_float4(h1[4 * c], h1[4 * c + 1], h1[4 * c + 2], h1[4 * c + 3]);
        }
    }

    // dual GEMM; weights from global (L1-resident 16KB working set)
    float aY0[8], aZ0[8], aY1[8], aZ1[8];
    #pragma unroll
    for (int jj = 0; jj < 8; jj++) {
        aY0[jj] = sby[q * 8 + jj]; aY1[jj] = aY0[jj];
        aZ0[jj] = 0.f; aZ1[jj] = 0.f;
    }
    #pragma unroll
    for (int kk = 0; kk < 16; kk++) {
        #pragma unroll
        for (int ss = 0; ss < 4; ss++) {
            float v0 = __shfl(h0[kk], ss, 4);
            float v1 = __shfl(h1[kk], ss, 4);
            int k = ss * 16 + kk;
            const float4* nw = (const float4*)(nodeW + k * 32 + q * 8);
            const float4* ew = (const float4*)(edgeW + k * 32 + q * 8);
            float4 a = nw[0], b = nw[1], c = ew[0], d = ew[1];
            ACC8(aY0, v0, a, b)
            ACC8(aZ0, v0, c, d)
            ACC8(aY1, v1, a, b)
            ACC8(aZ1, v1, c, d)
        }
    }
    float4* yv0 = (float4*)(Y + (size_t)n0 * 32 + q * 8);
    float4* zv0 = (float4*)(Z + (size_t)n0 * 32 + q * 8);
    float4* yv1 = (float4*)(Y + (size_t)n1 * 32 + q * 8);
    float4* zv1 = (float4*)(Z + (size_t)n1 * 32 + q * 8);
    yv0[0] = make_float4(aY0[0], aY0[1], aY0[2], aY0[3]);
    yv0[1] = make_float4(aY0[4], aY0[5], aY0[6], aY0[7]);
    zv0[0] = make_float4(aZ0[0], aZ0[1], aZ0[2], aZ0[3]);
    zv0[1] = make_float4(aZ0[4], aZ0[5], aZ0[6], aZ0[7]);
    yv1[0] = make_float4(aY1[0], aY1[1], aY1[2], aY1[3]);
    yv1[1] = make_float4(aY1[4], aY1[5], aY1[6], aY1[7]);
    zv1[0] = make_float4(aZ1[0], aZ1[1], aZ1[2], aZ1[3]);
    zv1[1] = make_float4(aZ1[4], aZ1[5], aZ1[6], aZ1[7]);
}

// ---------------------------------------------------------------------------
// Fallback gather (used only when workspace too small for Z ping-pong)
// ---------------------------------------------------------------------------
__global__ __launch_bounds__(256) void gather_kernel(
    const int* __restrict__ offs, const int2* __restrict__ ep,
    const float* __restrict__ Z, float* __restrict__ Y)
{
    int gid = blockIdx.x * 256 + threadIdx.x;
    int node = gid >> 3;
    int lane = gid & 7;
    if (node >= N_NODES) return;
    int p0 = offs[node], p1 = offs[node + 1];
    float4 acc = make_float4(0.f, 0.f, 0.f, 0.f);
    const float4* Zv = (const float4*)Z;
    int p = p0;
    for (; p + 4 <= p1; p += 4) {
        int2 ea = ep[p];
        int2 eb = ep[p + 1];
        int2 ec = ep[p + 2];
        int2 ed = ep[p + 3];
        float4 za = Zv[(size_t)ea.x * 8 + lane];
        float4 zb = Zv[(size_t)eb.x * 8 + lane];
        float4 zc = Zv[(size_t)ec.x * 8 + lane];
        float4 zd = Zv[(size_t)ed.x * 8 + lane];
        float wa = __int_as_float(ea.y);
        float wb = __int_as_float(eb.y);
        float wc = __int_as_float(ec.y);
        float wd = __int_as_float(ed.y);
        acc.x += wa * za.x + wb * zb.x + wc * zc.x + wd * zd.x;
        acc.y += wa * za.y + wb * zb.y + wc * zc.y + wd * zd.y;
        acc.z += wa * za.z + wb * zb.z + wc * zc.z + wd * zd.z;
        acc.w += wa * za.w + wb * zb.w + wc * zc.w + wd * zd.w;
    }
    for (; p < p1; p++) {
        int2 ea = ep[p];
        float wa = __int_as_float(ea.y);
        float4 za = Zv[(size_t)ea.x * 8 + lane];
        acc.x += wa * za.x; acc.y += wa * za.y;
        acc.z += wa * za.z; acc.w += wa * za.w;
    }
    float4* yp = (float4*)(Y + (size_t)node * 32) + lane;
    float4 y = *yp;
    y.x += acc.x; y.y += acc.y; y.z += acc.z; y.w += acc.w;
    *yp = y;
}

// ---------------------------------------------------------------------------
// Kernel B (fused): gather(layer l) + mlp+residual (layer l) + LN + dual GEMM
// (layer l+1).  4 lanes/node; lane q gathers its own cols [q*8,q*8+8).
// fuse==0 -> skip gather (fallback path runs gather_kernel first).
// Reads Zin, writes Zout (ping-pong; never the same buffer when fused).
// ---------------------------------------------------------------------------
__global__ __launch_bounds__(256) void mlp_ln_gemm(
    const int* __restrict__ offs, const int2* __restrict__ ep,
    const float* __restrict__ Zin,
    float* __restrict__ Yio, float* __restrict__ H, float* __restrict__ Zout,
    const float* __restrict__ mlpW, const float* __restrict__ mlp_b,
    const float* __restrict__ ln_g, const float* __restrict__ ln_b,
    const float* __restrict__ nodeW, const float* __restrict__ node_b,
    const float* __restrict__ edgeW, const float* __restrict__ edge_b,
    int fuse)
{
    __shared__ float sMW[32 * 64];
    __shared__ float sNW[64 * 32];
    __shared__ float sEW[64 * 32];
    __shared__ float smb[64], sg[64], sb[64], sby[32];
    for (int idx = threadIdx.x; idx < 32 * 64; idx += 256) sMW[idx] = mlpW[idx];
    for (int idx = threadIdx.x; idx < 64 * 32; idx += 256) {
        sNW[idx] = nodeW[idx];
        sEW[idx] = edgeW[idx];
    }
    if (threadIdx.x < 64) {
        smb[threadIdx.x] = mlp_b[threadIdx.x];
        sg[threadIdx.x] = ln_g[threadIdx.x];
        sb[threadIdx.x] = ln_b[threadIdx.x];
    }
    if (threadIdx.x < 32) sby[threadIdx.x] = node_b[threadIdx.x] + edge_b[threadIdx.x];
    __syncthreads();

    int gid = blockIdx.x * 256 + threadIdx.x;
    int node = gid >> 2;
    int q = gid & 3;
    if (node >= N_NODES) return;

    // gather into registers: lane q owns cols [q*8, q*8+8) = float4 slots 2q,2q+1
    float ga[8];
    #pragma unroll
    for (int j = 0; j < 8; j++) ga[j] = 0.f;
    if (fuse) {
        int p0 = offs[node], p1 = offs[node + 1];
        const float4* Zv = (const float4*)Zin;
        int p = p0;
        for (; p + 2 <= p1; p += 2) {
            int2 ea = ep[p];
            int2 eb = ep[p + 1];
            float4 za0 = Zv[(size_t)ea.x * 8 + 2 * q];
            float4 za1 = Zv[(size_t)ea.x * 8 + 2 * q + 1];
            float4 zb0 = Zv[(size_t)eb.x * 8 + 2 * q];
            float4 zb1 = Zv[(size_t)eb.x * 8 + 2 * q + 1];
            float wa = __int_as_float(ea.y);
            float wb = __int_as_float(eb.y);
            ga[0] += wa * za0.x + wb * zb0.x;
            ga[1] += wa * za0.y + wb * zb0.y;
            ga[2] += wa * za0.z + wb * zb0.z;
            ga[3] += wa * za0.w + wb * zb0.w;
            ga[4] += wa * za1.x + wb * zb1.x;
            ga[5] += wa * za1.y + wb * zb1.y;
            ga[6] += wa * za1.z + wb * zb1.z;
            ga[7] += wa * za1.w + wb * zb1.w;
        }
        if (p < p1) {
            int2 ea = ep[p];
            float4 za0 = Zv[(size_t)ea.x * 8 + 2 * q];
            float4 za1 = Zv[(size_t)ea.x * 8 + 2 * q + 1];
            float wa = __int_as_float(ea.y);
            ga[0] += wa * za0.x; ga[1] += wa * za0.y;
            ga[2] += wa * za0.z; ga[3] += wa * za0.w;
            ga[4] += wa * za1.x; ga[5] += wa * za1.y;
            ga[6] += wa * za1.z; ga[7] += wa * za1.w;
        }
    }

    float ly[8];
    const float4* yvin = (const float4*)(Yio + (size_t)node * 32 + q * 8);
    {
        float4 t0 = yvin[0], t1 = yvin[1];
        ly[0] = leaky(t0.x + ga[0]); ly[1] = leaky(t0.y + ga[1]);
        ly[2] = leaky(t0.z + ga[2]); ly[3] = leaky(t0.w + ga[3]);
        ly[4] = leaky(t1.x + ga[4]); ly[5] = leaky(t1.y + ga[5]);
        ly[6] = leaky(t1.z + ga[6]); ly[7] = leaky(t1.w + ga[7]);
    }
    float h[16];
    #pragma unroll
    for (int jj = 0; jj < 16; jj++) h[jj] = smb[q * 16 + jj];
    #pragma unroll
    for (int kk = 0; kk < 8; kk++) {
        #pragma unroll
        for (int ss = 0; ss < 4; ss++) {
            float v = __shfl(ly[kk], ss, 4);
            const float4* w = (const float4*)(sMW + (ss * 8 + kk) * 64 + q * 16);
            float4 a = w[0], b = w[1], c = w[2], d = w[3];
            ACC16(h, v, a, b, c, d)
        }
    }
    float4* hp = (float4*)(H + (size_t)node * 64 + q * 16);
    #pragma unroll
    for (int c = 0; c < 4; c++) {
        float4 r = hp[c];
        h[4 * c] += r.x; h[4 * c + 1] += r.y; h[4 * c + 2] += r.z; h[4 * c + 3] += r.w;
    }
    float s = 0.f, s2 = 0.f;
    #pragma unroll
    for (int jj = 0; jj < 16; jj++) { s += h[jj]; s2 += h[jj] * h[jj]; }
    s  += __shfl_xor(s, 1, 4);  s  += __shfl_xor(s, 2, 4);
    s2 += __shfl_xor(s2, 1, 4); s2 += __shfl_xor(s2, 2, 4);
    float mu  = s * (1.f / 64.f);
    float var = s2 * (1.f / 64.f) - mu * mu;
    float rs  = rsqrtf(var + 1e-5f);

    float hn[16];
    #pragma unroll
    for (int jj = 0; jj < 16; jj++)
        hn[jj] = (h[jj] - mu) * rs * sg[q * 16 + jj] + sb[q * 16 + jj];
    #pragma unroll
    for (int c = 0; c < 4; c++)
        hp[c] = make_float4(hn[4 * c], hn[4 * c + 1], hn[4 * c + 2], hn[4 * c + 3]);

    float aY[8], aZ[8];
    #pragma unroll
    for (int jj = 0; jj < 8; jj++) { aY[jj] = sby[q * 8 + jj]; aZ[jj] = 0.f; }
    #pragma unroll
    for (int kk = 0; kk < 16; kk++) {
        #pragma unroll
        for (int ss = 0; ss < 4; ss++) {
            float v = __shfl(hn[kk], ss, 4);
            int k = ss * 16 + kk;
            const float4* nw = (const float4*)(sNW + k * 32 + q * 8);
            const float4* ew = (const float4*)(sEW + k * 32 + q * 8);
            float4 a = nw[0], b = nw[1], c = ew[0], d = ew[1];
            ACC8(aY, v, a, b)
            ACC8(aZ, v, c, d)
        }
    }
    float4* yo = (float4*)(Yio + (size_t)node * 32 + q * 8);
    float4* zv = (float4*)(Zout + (size_t)node * 32 + q * 8);
    yo[0] = make_float4(aY[0], aY[1], aY[2], aY[3]);
    yo[1] = make_float4(aY[4], aY[5], aY[6], aY[7]);
    zv[0] = make_float4(aZ[0], aZ[1], aZ[2], aZ[3]);
    zv[1] = make_float4(aZ[4], aZ[5], aZ[6], aZ[7]);
}

// ---------------------------------------------------------------------------
// Kernel C (fused): gather(layer 3) + mlp+residual (layer 3) + decoder.
// ---------------------------------------------------------------------------
__global__ __launch_bounds__(256) void mlp_dec(
    const int* __restrict__ offs, const int2* __restrict__ ep,
    const float* __restrict__ Zin,
    const float* __restrict__ Y, const float* __restrict__ H,
    const float* __restrict__ mlpW, const float* __restrict__ mlp_b,
    const float* __restrict__ dW1, const float* __restrict__ db1,
    const float* __restrict__ dW2, const float* __restrict__ db2,
    float* __restrict__ out, int fuse)
{
    __shared__ float sMW[32 * 64];
    __shared__ float smb[64];
    __shared__ float sW1t[24 * 65];
    __shared__ float sb1[24];
    __shared__ float sW2[24 * 3];
    __shared__ float sb2v[3];
    for (int idx = threadIdx.x; idx < 32 * 64; idx += 256) sMW[idx] = mlpW[idx];
    for (int idx = threadIdx.x; idx < 64 * 24; idx += 256) {
        int k = idx / 24, t = idx % 24;
        sW1t[t * 65 + k] = dW1[idx];
    }
    if (threadIdx.x < 64) smb[threadIdx.x] = mlp_b[threadIdx.x];
    if (threadIdx.x < 24) sb1[threadIdx.x] = db1[threadIdx.x];
    if (threadIdx.x < 72) sW2[threadIdx.x] = dW2[threadIdx.x];
    if (threadIdx.x < 3)  sb2v[threadIdx.x] = db2[threadIdx.x];
    __syncthreads();

    int gid = blockIdx.x * 256 + threadIdx.x;
    int node = gid >> 2;
    int q = gid & 3;
    if (node >= N_NODES) return;

    float ga[8];
    #pragma unroll
    for (int j = 0; j < 8; j++) ga[j] = 0.f;
    if (fuse) {
        int p0 = offs[node], p1 = offs[node + 1];
        const float4* Zv = (const float4*)Zin;
        int p = p0;
        for (; p + 2 <= p1; p += 2) {
            int2 ea = ep[p];
            int2 eb = ep[p + 1];
            float4 za0 = Zv[(size_t)ea.x * 8 + 2 * q];
            float4 za1 = Zv[(size_t)ea.x * 8 + 2 * q + 1];
            float4 zb0 = Zv[(size_t)eb.x * 8 + 2 * q];
            float4 zb1 = Zv[(size_t)eb.x * 8 + 2 * q + 1];
            float wa = __int_as_float(ea.y);
            float wb = __int_as_float(eb.y);
            ga[0] += wa * za0.x + wb * zb0.x;
            ga[1] += wa * za0.y + wb * zb0.y;
            ga[2] += wa * za0.z + wb * zb0.z;
            ga[3] += wa * za0.w + wb * zb0.w;
            ga[4] += wa * za1.x + wb * zb1.x;
            ga[5] += wa * za1.y + wb * zb1.y;
            ga[6] += wa * za1.z + wb * zb1.z;
            ga[7] += wa * za1.w + wb * zb1.w;
        }
        if (p < p1) {
            int2 ea = ep[p];
            float4 za0 = Zv[(size_t)ea.x * 8 + 2 * q];
            float4 za1 = Zv[(size_t)ea.x * 8 + 2 * q + 1];
            float wa = __int_as_float(ea.y);
            ga[0] += wa * za0.x; ga[1] += wa * za0.y;
            ga[2] += wa * za0.z; ga[3] += wa * za0.w;
            ga[4] += wa * za1.x; ga[5] += wa * za1.y;
            ga[6] += wa * za1.z; ga[7] += wa * za1.w;
        }
    }

    float ly[8];
    const float4* yvin = (const float4*)(Y + (size_t)node * 32 + q * 8);
    {
        float4 t0 = yvin[0], t1 = yvin[1];
        ly[0] = leaky(t0.x + ga[0]); ly[1] = leaky(t0.y + ga[1]);
        ly[2] = leaky(t0.z + ga[2]); ly[3] = leaky(t0.w + ga[3]);
        ly[4] = leaky(t1.x + ga[4]); ly[5] = leaky(t1.y + ga[5]);
        ly[6] = leaky(t1.z + ga[6]); ly[7] = leaky(t1.w + ga[7]);
    }
    float h[16];
    #pragma unroll
    for (int jj = 0; jj < 16; jj++) h[jj] = smb[q * 16 + jj];
    #pragma unroll
    for (int kk = 0; kk < 8; kk++) {
        #pragma unroll
        for (int ss = 0; ss < 4; ss++) {
            float v = __shfl(ly[kk], ss, 4);
            const float4* w = (const float4*)(sMW + (ss * 8 + kk) * 64 + q * 16);
            float4 a = w[0], b = w[1], c = w[2], d = w[3];
            ACC16(h, v, a, b, c, d)
        }
    }
    const float4* hp = (const float4*)(H + (size_t)node * 64 + q * 16);
    #pragma unroll
    for (int c = 0; c < 4; c++) {
        float4 r = hp[c];
        h[4 * c] += r.x; h[4 * c + 1] += r.y; h[4 * c + 2] += r.z; h[4 * c + 3] += r.w;
    }
    float hid[6];
    #pragma unroll
    for (int t = 0; t < 6; t++) hid[t] = sb1[q * 6 + t];
    #pragma unroll
    for (int kk = 0; kk < 16; kk++) {
        #pragma unroll
        for (int ss = 0; ss < 4; ss++) {
            float v = __shfl(h[kk], ss, 4);
            int k = ss * 16 + kk;
            #pragma unroll
            for (int t = 0; t < 6; t++)
                hid[t] += v * sW1t[(q * 6 + t) * 65 + k];
        }
    }
    float o0 = 0.f, o1 = 0.f, o2 = 0.f;
    #pragma unroll
    for (int t = 0; t < 6; t++) {
        float lt = leaky(hid[t]);
        int tg = q * 6 + t;
        o0 += lt * sW2[tg * 3 + 0];
        o1 += lt * sW2[tg * 3 + 1];
        o2 += lt * sW2[tg * 3 + 2];
    }
    o0 += __shfl_xor(o0, 1, 4); o0 += __shfl_xor(o0, 2, 4);
    o1 += __shfl_xor(o1, 1, 4); o1 += __shfl_xor(o1, 2, 4);
    o2 += __shfl_xor(o2, 1, 4); o2 += __shfl_xor(o2, 2, 4);
    if (q == 0) {
        float* op = out + (size_t)node * 3;
        op[0] = o0 + sb2v[0]; op[1] = o1 + sb2v[1]; op[2] = o2 + sb2v[2];
    }
}

// ---------------------------------------------------------------------------
extern "C" void kernel_launch(void* const* d_in, const int* in_sizes, int n_in,
                              void* d_out, int out_size, void* d_ws, size_t ws_size,
                              hipStream_t stream)
{
    const float* x      = (const float*)d_in[0];
    const int*   esrc   = (const int*)d_in[2];
    const int*   edst   = (const int*)d_in[3];
    const float* ew     = (const float*)d_in[4];
    const float* enc_W1 = (const float*)d_in[5];
    const float* enc_b1 = (const float*)d_in[6];
    const float* enc_W2 = (const float*)d_in[7];
    const float* enc_b2 = (const float*)d_in[8];
    const float* dec_W1 = (const float*)d_in[9];
    const float* dec_b1 = (const float*)d_in[10];
    const float* dec_W2 = (const float*)d_in[11];
    const float* dec_b2 = (const float*)d_in[12];
    const float* ln_g   = (const float*)d_in[13];
    const float* ln_b   = (const float*)d_in[14];
    const float* node_W = (const float*)d_in[15];
    const float* node_b = (const float*)d_in[16];
    const float* edge_W = (const float*)d_in[17];
    const float* edge_b = (const float*)d_in[18];
    const float* mlp_W  = (const float*)d_in[19];
    const float* mlp_b  = (const float*)d_in[20];

    // Workspace: H[N*64] | Y[N*32] | Za[N*32] | ep | offs | Hg | T | BS | [Zb]
    float* H  = (float*)d_ws;
    float* Y  = H + (size_t)N_NODES * 64;
    float* Za = Y + (size_t)N_NODES * 32;
    int2*  ep = (int2*)(Za + (size_t)N_NODES * 32);
    int* offs = (int*)(ep + N_EDGES);
    int* Hg   = offs + N_NODES + 1;
    int* T    = Hg + NBLK * NB2;
    int* BS   = T + NB2;
    float* Zb = (float*)(BS + NB2 + 2);      // only used when ws permits
    size_t needed = ((char*)(Zb + (size_t)N_NODES * 32)) - (char*)d_ws;
    int fuse = (ws_size >= needed) ? 1 : 0;
    if (!fuse) Zb = Za;                      // fallback: single Z buffer
    // bucket-sorted edge scratch aliases H (dead until enc_ln_gemm)
    int2* sE  = (int2*)H;

    const int pairBlocks   = (NPAIR * 4 + 255) / 256;
    const int node4Blocks  = (N_NODES * 4 + 255) / 256;
    const int gatherBlocks = (N_NODES * 8 + 255) / 256;

    // --- CSR build (zero global atomics) ---
    hist_k<<<NBLK, 256, 0, stream>>>(edst, Hg);
    scan_blocks_k<<<NB2, NBLK, 0, stream>>>(Hg, T);
    scan_T_k<<<1, 256, 0, stream>>>(T, BS);
    scatter_k<<<NBLK, 256, 0, stream>>>(esrc, edst, ew, Hg, BS, sE);
    finalize_k<<<NB2, 256, 0, stream>>>(BS, sE, offs, ep);

    // --- network ---
    enc_ln_gemm<<<pairBlocks, 256, 0, stream>>>(
        x, enc_W1, enc_b1, enc_W2, enc_b2,
        ln_g, ln_b, node_W, node_b, edge_W, edge_b, H, Y, Za);

    float* zin = Za;
    float* zout = fuse ? Zb : Za;
    for (int l = 0; l < LAYERS - 1; l++) {
        if (!fuse)
            gather_kernel<<<gatherBlocks, 256, 0, stream>>>(offs, ep, zin, Y);
        mlp_ln_gemm<<<node4Blocks, 256, 0, stream>>>(
            offs, ep, zin, Y, H, zout,
            mlp_W + l * 32 * 64, mlp_b + l * 64,
            ln_g + (l + 1) * 64, ln_b + (l + 1) * 64,
            node_W + (l + 1) * 64 * 32, node_b + (l + 1) * 32,
            edge_W + (l + 1) * 64 * 32, edge_b + (l + 1) * 32, fuse);
        if (fuse) { float* t = zin; zin = zout; zout = t; }
    }
    if (!fuse)
        gather_kernel<<<gatherBlocks, 256, 0, stream>>>(offs, ep, zin, Y);
    mlp_dec<<<node4Blocks, 256, 0, stream>>>(
        offs, ep, zin, Y, H,
        mlp_W + 3 * 32 * 64, mlp_b + 3 * 64,
        dec_W1, dec_b1, dec_W2, dec_b2, (float*)d_out, fuse);
}

// Round 8
// 468.512 us; speedup vs baseline: 1.0837x; 1.0837x over previous
//
#include <hip/hip_runtime.h>

#define N_NODES 100000
#define N_EDGES 1200000
#define LAYERS 4
#define SLOPE 0.01f

#define NPAIR (N_NODES / 2)                 // 50000 (N even)

// two-level zero-atomic counting sort
#define BUCKET_SHIFT 7
#define NB2 ((N_NODES + 127) >> 7)          // 782 buckets of 128 nodes
#define NBLK 128                            // scatter blocks
#define EPB (N_EDGES / NBLK)                // 9375 (exact)

__device__ __forceinline__ float leaky(float v) { return v >= 0.f ? v : SLOPE * v; }

#define ACC16(h, v, a, b, c, d) \
    h[0]  += v * a.x; h[1]  += v * a.y; h[2]  += v * a.z; h[3]  += v * a.w; \
    h[4]  += v * b.x; h[5]  += v * b.y; h[6]  += v * b.z; h[7]  += v * b.w; \
    h[8]  += v * c.x; h[9]  += v * c.y; h[10] += v * c.z; h[11] += v * c.w; \
    h[12] += v * d.x; h[13] += v * d.y; h[14] += v * d.z; h[15] += v * d.w;

#define ACC8(r, v, a, b) \
    r[0] += v * a.x; r[1] += v * a.y; r[2] += v * a.z; r[3] += v * a.w; \
    r[4] += v * b.x; r[5] += v * b.y; r[6] += v * b.z; r[7] += v * b.w;

// ---------------------------------------------------------------------------
// CSR build — zero global atomics (round-4 form, verified).
// ---------------------------------------------------------------------------
__global__ __launch_bounds__(256) void hist_k(
    const int* __restrict__ dst, int* __restrict__ Hg)
{
    __shared__ int lh[NB2];
    for (int i = threadIdx.x; i < NB2; i += 256) lh[i] = 0;
    __syncthreads();
    int blk = blockIdx.x;
    int e1 = blk * EPB + EPB;
    for (int e = blk * EPB + threadIdx.x; e < e1; e += 256)
        atomicAdd(&lh[dst[e] >> BUCKET_SHIFT], 1);
    __syncthreads();
    for (int i = threadIdx.x; i < NB2; i += 256) Hg[blk * NB2 + i] = lh[i];
}

__global__ __launch_bounds__(NBLK) void scan_blocks_k(
    int* __restrict__ Hg, int* __restrict__ T)
{
    __shared__ int s[NBLK];
    int b = blockIdx.x, t = threadIdx.x;
    int v = Hg[t * NB2 + b];
    s[t] = v; __syncthreads();
    for (int off = 1; off < NBLK; off <<= 1) {
        int y = (t >= off) ? s[t - off] : 0;
        __syncthreads();
        s[t] += y;
        __syncthreads();
    }
    Hg[t * NB2 + b] = s[t] - v;
    if (t == NBLK - 1) T[b] = s[t];
}

__global__ __launch_bounds__(256) void scan_T_k(
    const int* __restrict__ T, int* __restrict__ BS)
{
    __shared__ int s[256];
    int t = threadIdx.x;
    int beg = t * 4, end = beg + 4 > NB2 ? NB2 : beg + 4;
    int v[4]; int sum = 0;
    for (int i = beg, u = 0; i < end; i++, u++) { v[u] = sum; sum += T[i]; }
    s[t] = sum; __syncthreads();
    for (int off = 1; off < 256; off <<= 1) {
        int y = (t >= off) ? s[t - off] : 0;
        __syncthreads();
        s[t] += y;
        __syncthreads();
    }
    int excl = s[t] - sum;
    for (int i = beg, u = 0; i < end; i++, u++) BS[i] = excl + v[u];
    if (t == 0) BS[NB2] = N_EDGES;
}

__global__ __launch_bounds__(256) void scatter_k(
    const int* __restrict__ src, const int* __restrict__ dst,
    const float* __restrict__ w, const int* __restrict__ Hg,
    const int* __restrict__ BS, int2* __restrict__ sE)
{
    __shared__ int cur[NB2];
    int blk = blockIdx.x;
    for (int i = threadIdx.x; i < NB2; i += 256)
        cur[i] = BS[i] + Hg[blk * NB2 + i];
    __syncthreads();
    int e1 = blk * EPB + EPB;
    for (int e = blk * EPB + threadIdx.x; e < e1; e += 256) {
        int d = dst[e];
        int p = atomicAdd(&cur[d >> BUCKET_SHIFT], 1);
        sE[p] = make_int2(src[e] | ((d & 127) << 17), __float_as_int(w[e]));
    }
}

__global__ __launch_bounds__(256) void finalize_k(
    const int* __restrict__ BS, const int2* __restrict__ sE,
    int* __restrict__ offs, int2* __restrict__ ep)
{
    __shared__ int cnt[128];
    __shared__ int s[128];
    __shared__ int cur[128];
    int b = blockIdx.x, t = threadIdx.x;
    int s0 = BS[b], s1 = BS[b + 1];
    if (t < 128) cnt[t] = 0;
    __syncthreads();
    for (int i = s0 + t; i < s1; i += 256)
        atomicAdd(&cnt[(sE[i].x >> 17) & 127], 1);
    __syncthreads();
    int v = 0;
    if (t < 128) { v = cnt[t]; s[t] = v; }
    __syncthreads();
    for (int off = 1; off < 128; off <<= 1) {
        int y = (t >= off && t < 128) ? s[t - off] : 0;
        __syncthreads();
        if (t < 128) s[t] += y;
        __syncthreads();
    }
    if (t < 128) {
        int excl = s[t] - v;
        cur[t] = s0 + excl;
        int node = b * 128 + t;
        if (node < N_NODES) offs[node] = s0 + excl;
    }
    if (b == NB2 - 1 && t == 0) offs[N_NODES] = N_EDGES;
    __syncthreads();
    for (int i = s0 + t; i < s1; i += 256) {
        int2 e = sE[i];
        int p = atomicAdd(&cur[(e.x >> 17) & 127], 1);
        ep[p] = make_int2(e.x & 0x1FFFF, e.y);
    }
}

// ---------------------------------------------------------------------------
// Kernel A: encoder + LN(layer0) + dual GEMM(layer0).  Round-5 verbatim:
// 4 lanes x 2 nodes per thread, stage-1 fused, ALL weights LDS-staged
// (global weights in the inner loop measured +36us in round 6 — never again).
// ---------------------------------------------------------------------------
__global__ __launch_bounds__(256, 2) void enc_ln_gemm(
    const float* __restrict__ x,
    const float* __restrict__ W1, const float* __restrict__ b1,
    const float* __restrict__ W2, const float* __restrict__ b2,
    const float* __restrict__ ln_g, const float* __restrict__ ln_b,
    const float* __restrict__ nodeW, const float* __restrict__ node_b,
    const float* __restrict__ edgeW, const float* __restrict__ edge_b,
    float* __restrict__ H, float* __restrict__ Y, float* __restrict__ Z)
{
    __shared__ float sW1t[128 * 16];   // [k][i] = W1[i][k]
    __shared__ float sW2[128 * 64];
    __shared__ float sNW[64 * 32];
    __shared__ float sEW[64 * 32];
    __shared__ float sb1[128];
    __shared__ float sb2[64];
    __shared__ float sg[64], sb[64], sby[32];
    for (int idx = threadIdx.x; idx < 16 * 128; idx += 256) {
        int i = idx / 128, k = idx % 128;
        sW1t[k * 16 + i] = W1[idx];
    }
    for (int idx = threadIdx.x; idx < 128 * 64; idx += 256) sW2[idx] = W2[idx];
    for (int idx = threadIdx.x; idx < 64 * 32; idx += 256) {
        sNW[idx] = nodeW[idx];
        sEW[idx] = edgeW[idx];
    }
    if (threadIdx.x < 128) sb1[threadIdx.x] = b1[threadIdx.x];
    if (threadIdx.x < 64) {
        sb2[threadIdx.x] = b2[threadIdx.x];
        sg[threadIdx.x] = ln_g[threadIdx.x];
        sb[threadIdx.x] = ln_b[threadIdx.x];
    }
    if (threadIdx.x < 32) sby[threadIdx.x] = node_b[threadIdx.x] + edge_b[threadIdx.x];
    __syncthreads();

    int base = blockIdx.x * 256 + threadIdx.x;
    int pair = base >> 2;
    int q = base & 3;
    if (pair >= NPAIR) return;
    int n0 = pair * 2, n1 = n0 + 1;

    float xi0[16], xi1[16];
    {
        const float4* xv0 = (const float4*)(x + (size_t)n0 * 16);
        const float4* xv1 = (const float4*)(x + (size_t)n1 * 16);
        #pragma unroll
        for (int i = 0; i < 4; i++) {
            float4 t = xv0[i];
            xi0[4 * i] = t.x; xi0[4 * i + 1] = t.y; xi0[4 * i + 2] = t.z; xi0[4 * i + 3] = t.w;
            float4 u = xv1[i];
            xi1[4 * i] = u.x; xi1[4 * i + 1] = u.y; xi1[4 * i + 2] = u.z; xi1[4 * i + 3] = u.w;
        }
    }

    float h0[16], h1[16];
    #pragma unroll
    for (int jj = 0; jj < 16; jj++) { h0[jj] = sb2[q * 16 + jj]; h1[jj] = h0[jj]; }
    #pragma unroll 4
    for (int kk = 0; kk < 32; kk++) {
        int t = kk * 4 + q;
        const float4* wv = (const float4*)(sW1t + t * 16);
        float4 w0 = wv[0], w1 = wv[1], w2 = wv[2], w3 = wv[3];
        float a0 = sb1[t];
        a0 += xi0[0] * w0.x + xi0[1] * w0.y + xi0[2] * w0.z + xi0[3] * w0.w;
        a0 += xi0[4] * w1.x + xi0[5] * w1.y + xi0[6] * w1.z + xi0[7] * w1.w;
        a0 += xi0[8] * w2.x + xi0[9] * w2.y + xi0[10] * w2.z + xi0[11] * w2.w;
        a0 += xi0[12] * w3.x + xi0[13] * w3.y + xi0[14] * w3.z + xi0[15] * w3.w;
        float a1 = sb1[t];
        a1 += xi1[0] * w0.x + xi1[1] * w0.y + xi1[2] * w0.z + xi1[3] * w0.w;
        a1 += xi1[4] * w1.x + xi1[5] * w1.y + xi1[6] * w1.z + xi1[7] * w1.w;
        a1 += xi1[8] * w2.x + xi1[9] * w2.y + xi1[10] * w2.z + xi1[11] * w2.w;
        a1 += xi1[12] * w3.x + xi1[13] * w3.y + xi1[14] * w3.z + xi1[15] * w3.w;
        float hv0 = leaky(a0);
        float hv1 = leaky(a1);
        #pragma unroll
        for (int ss = 0; ss < 4; ss++) {
            float v0 = __shfl(hv0, ss, 4);
            float v1 = __shfl(hv1, ss, 4);
            const float4* w = (const float4*)(sW2 + (kk * 4 + ss) * 64 + q * 16);
            float4 aa = w[0], bb = w[1], cc = w[2], dd = w[3];
            ACC16(h0, v0, aa, bb, cc, dd)
            ACC16(h1, v1, aa, bb, cc, dd)
        }
    }

    // LN over quad (both nodes)
    float s0 = 0.f, e0 = 0.f, s1 = 0.f, e1 = 0.f;
    #pragma unroll
    for (int jj = 0; jj < 16; jj++) {
        s0 += h0[jj]; e0 += h0[jj] * h0[jj];
        s1 += h1[jj]; e1 += h1[jj] * h1[jj];
    }
    s0 += __shfl_xor(s0, 1, 4); s0 += __shfl_xor(s0, 2, 4);
    e0 += __shfl_xor(e0, 1, 4); e0 += __shfl_xor(e0, 2, 4);
    s1 += __shfl_xor(s1, 1, 4); s1 += __shfl_xor(s1, 2, 4);
    e1 += __shfl_xor(e1, 1, 4); e1 += __shfl_xor(e1, 2, 4);
    float mu0 = s0 * (1.f / 64.f);
    float va0 = e0 * (1.f / 64.f) - mu0 * mu0;
    float r0  = rsqrtf(va0 + 1e-5f);
    float mu1 = s1 * (1.f / 64.f);
    float va1 = e1 * (1.f / 64.f) - mu1 * mu1;
    float r1  = rsqrtf(va1 + 1e-5f);

    #pragma unroll
    for (int jj = 0; jj < 16; jj++) {
        float g = sg[q * 16 + jj], bb = sb[q * 16 + jj];
        h0[jj] = (h0[jj] - mu0) * r0 * g + bb;   // hn in place
        h1[jj] = (h1[jj] - mu1) * r1 * g + bb;
    }
    {
        float4* hs0 = (float4*)(H + (size_t)n0 * 64 + q * 16);
        float4* hs1 = (float4*)(H + (size_t)n1 * 64 + q * 16);
        #pragma unroll
        for (int c = 0; c < 4; c++) {
            hs0[c] = make_float4(h0[4 * c], h0[4 * c + 1], h0[4 * c + 2], h0[4 * c + 3]);
            hs1[c] = make_float4(h1[4 * c], h1[4 * c + 1], h1[4 * c + 2], h1[4 * c + 3]);
        }
    }

    float aY0[8], aZ0[8], aY1[8], aZ1[8];
    #pragma unroll
    for (int jj = 0; jj < 8; jj++) {
        aY0[jj] = sby[q * 8 + jj]; aY1[jj] = aY0[jj];
        aZ0[jj] = 0.f; aZ1[jj] = 0.f;
    }
    #pragma unroll
    for (int kk = 0; kk < 16; kk++) {
        #pragma unroll
        for (int ss = 0; ss < 4; ss++) {
            float v0 = __shfl(h0[kk], ss, 4);
            float v1 = __shfl(h1[kk], ss, 4);
            int k = ss * 16 + kk;
            const float4* nw = (const float4*)(sNW + k * 32 + q * 8);
            const float4* ew = (const float4*)(sEW + k * 32 + q * 8);
            float4 a = nw[0], b = nw[1], c = ew[0], d = ew[1];
            ACC8(aY0, v0, a, b)
            ACC8(aZ0, v0, c, d)
            ACC8(aY1, v1, a, b)
            ACC8(aZ1, v1, c, d)
        }
    }
    float4* yv0 = (float4*)(Y + (size_t)n0 * 32 + q * 8);
    float4* zv0 = (float4*)(Z + (size_t)n0 * 32 + q * 8);
    float4* yv1 = (float4*)(Y + (size_t)n1 * 32 + q * 8);
    float4* zv1 = (float4*)(Z + (size_t)n1 * 32 + q * 8);
    yv0[0] = make_float4(aY0[0], aY0[1], aY0[2], aY0[3]);
    yv0[1] = make_float4(aY0[4], aY0[5], aY0[6], aY0[7]);
    zv0[0] = make_float4(aZ0[0], aZ0[1], aZ0[2], aZ0[3]);
    zv0[1] = make_float4(aZ0[4], aZ0[5], aZ0[6], aZ0[7]);
    yv1[0] = make_float4(aY1[0], aY1[1], aY1[2], aY1[3]);
    yv1[1] = make_float4(aY1[4], aY1[5], aY1[6], aY1[7]);
    zv1[0] = make_float4(aZ1[0], aZ1[1], aZ1[2], aZ1[3]);
    zv1[1] = make_float4(aZ1[4], aZ1[5], aZ1[6], aZ1[7]);
}

// ---------------------------------------------------------------------------
// Gather: Y[n] += sum_e w_e * Z[src_e].  16 lanes/node: two 8-lane groups
// each sum half the edge list (sequential within group), combined via
// shfl_xor across the group boundary.  Doubles resident waves + halves
// per-lane dependency chains on the latency-bound random Z reads.
// ---------------------------------------------------------------------------
__global__ __launch_bounds__(256) void gather_kernel(
    const int* __restrict__ offs, const int2* __restrict__ ep,
    const float* __restrict__ Z, float* __restrict__ Y)
{
    int gid = blockIdx.x * 256 + threadIdx.x;
    int node = gid >> 4;
    int lane = gid & 7;            // column float4 within Z row
    int sub  = (gid >> 3) & 1;     // which edge-half
    if (node >= N_NODES) return;
    int p0 = offs[node], p1 = offs[node + 1];
    int mid = p0 + ((p1 - p0 + 1) >> 1);
    int a = sub ? mid : p0;
    int b = sub ? p1 : mid;
    float4 acc = make_float4(0.f, 0.f, 0.f, 0.f);
    const float4* Zv = (const float4*)Z;
    int p = a;
    for (; p + 2 <= b; p += 2) {
        int2 ea = ep[p];
        int2 eb = ep[p + 1];
        float4 za = Zv[(size_t)ea.x * 8 + lane];
        float4 zb = Zv[(size_t)eb.x * 8 + lane];
        float wa = __int_as_float(ea.y);
        float wb = __int_as_float(eb.y);
        acc.x += wa * za.x + wb * zb.x;
        acc.y += wa * za.y + wb * zb.y;
        acc.z += wa * za.z + wb * zb.z;
        acc.w += wa * za.w + wb * zb.w;
    }
    if (p < b) {
        int2 ea = ep[p];
        float wa = __int_as_float(ea.y);
        float4 za = Zv[(size_t)ea.x * 8 + lane];
        acc.x += wa * za.x; acc.y += wa * za.y;
        acc.z += wa * za.z; acc.w += wa * za.w;
    }
    // combine the two edge-halves (A + B, deterministic)
    acc.x += __shfl_xor(acc.x, 8, 16);
    acc.y += __shfl_xor(acc.y, 8, 16);
    acc.z += __shfl_xor(acc.z, 8, 16);
    acc.w += __shfl_xor(acc.w, 8, 16);
    if (sub == 0) {
        float4* yp = (float4*)(Y + (size_t)node * 32) + lane;
        float4 y = *yp;
        y.x += acc.x; y.y += acc.y; y.z += acc.z; y.w += acc.w;
        *yp = y;
    }
}

// ---------------------------------------------------------------------------
// Kernel B: mlp+residual (layer l) then LN + dual GEMM (layer l+1).
// Round-5 verbatim.
// ---------------------------------------------------------------------------
__global__ __launch_bounds__(256) void mlp_ln_gemm(
    float* __restrict__ Yio, float* __restrict__ H, float* __restrict__ Z,
    const float* __restrict__ mlpW, const float* __restrict__ mlp_b,
    const float* __restrict__ ln_g, const float* __restrict__ ln_b,
    const float* __restrict__ nodeW, const float* __restrict__ node_b,
    const float* __restrict__ edgeW, const float* __restrict__ edge_b)
{
    __shared__ float sMW[32 * 64];
    __shared__ float sNW[64 * 32];
    __shared__ float sEW[64 * 32];
    __shared__ float smb[64], sg[64], sb[64], sby[32];
    for (int idx = threadIdx.x; idx < 32 * 64; idx += 256) sMW[idx] = mlpW[idx];
    for (int idx = threadIdx.x; idx < 64 * 32; idx += 256) {
        sNW[idx] = nodeW[idx];
        sEW[idx] = edgeW[idx];
    }
    if (threadIdx.x < 64) {
        smb[threadIdx.x] = mlp_b[threadIdx.x];
        sg[threadIdx.x] = ln_g[threadIdx.x];
        sb[threadIdx.x] = ln_b[threadIdx.x];
    }
    if (threadIdx.x < 32) sby[threadIdx.x] = node_b[threadIdx.x] + edge_b[threadIdx.x];
    __syncthreads();

    int gid = blockIdx.x * 256 + threadIdx.x;
    int node = gid >> 2;
    int q = gid & 3;
    if (node >= N_NODES) return;

    float ly[8];
    const float4* yvin = (const float4*)(Yio + (size_t)node * 32 + q * 8);
    {
        float4 t0 = yvin[0], t1 = yvin[1];
        ly[0] = leaky(t0.x); ly[1] = leaky(t0.y); ly[2] = leaky(t0.z); ly[3] = leaky(t0.w);
        ly[4] = leaky(t1.x); ly[5] = leaky(t1.y); ly[6] = leaky(t1.z); ly[7] = leaky(t1.w);
    }
    float h[16];
    #pragma unroll
    for (int jj = 0; jj < 16; jj++) h[jj] = smb[q * 16 + jj];
    #pragma unroll
    for (int kk = 0; kk < 8; kk++) {
        #pragma unroll
        for (int ss = 0; ss < 4; ss++) {
            float v = __shfl(ly[kk], ss, 4);
            const float4* w = (const float4*)(sMW + (ss * 8 + kk) * 64 + q * 16);
            float4 a = w[0], b = w[1], c = w[2], d = w[3];
            ACC16(h, v, a, b, c, d)
        }
    }
    float4* hp = (float4*)(H + (size_t)node * 64 + q * 16);
    #pragma unroll
    for (int c = 0; c < 4; c++) {
        float4 r = hp[c];
        h[4 * c] += r.x; h[4 * c + 1] += r.y; h[4 * c + 2] += r.z; h[4 * c + 3] += r.w;
    }
    float s = 0.f, s2 = 0.f;
    #pragma unroll
    for (int jj = 0; jj < 16; jj++) { s += h[jj]; s2 += h[jj] * h[jj]; }
    s  += __shfl_xor(s, 1, 4);  s  += __shfl_xor(s, 2, 4);
    s2 += __shfl_xor(s2, 1, 4); s2 += __shfl_xor(s2, 2, 4);
    float mu  = s * (1.f / 64.f);
    float var = s2 * (1.f / 64.f) - mu * mu;
    float rs  = rsqrtf(var + 1e-5f);

    float hn[16];
    #pragma unroll
    for (int jj = 0; jj < 16; jj++)
        hn[jj] = (h[jj] - mu) * rs * sg[q * 16 + jj] + sb[q * 16 + jj];
    #pragma unroll
    for (int c = 0; c < 4; c++)
        hp[c] = make_float4(hn[4 * c], hn[4 * c + 1], hn[4 * c + 2], hn[4 * c + 3]);

    float aY[8], aZ[8];
    #pragma unroll
    for (int jj = 0; jj < 8; jj++) { aY[jj] = sby[q * 8 + jj]; aZ[jj] = 0.f; }
    #pragma unroll
    for (int kk = 0; kk < 16; kk++) {
        #pragma unroll
        for (int ss = 0; ss < 4; ss++) {
            float v = __shfl(hn[kk], ss, 4);
            int k = ss * 16 + kk;
            const float4* nw = (const float4*)(sNW + k * 32 + q * 8);
            const float4* ew = (const float4*)(sEW + k * 32 + q * 8);
            float4 a = nw[0], b = nw[1], c = ew[0], d = ew[1];
            ACC8(aY, v, a, b)
            ACC8(aZ, v, c, d)
        }
    }
    float4* yo = (float4*)(Yio + (size_t)node * 32 + q * 8);
    float4* zv = (float4*)(Z + (size_t)node * 32 + q * 8);
    yo[0] = make_float4(aY[0], aY[1], aY[2], aY[3]);
    yo[1] = make_float4(aY[4], aY[5], aY[6], aY[7]);
    zv[0] = make_float4(aZ[0], aZ[1], aZ[2], aZ[3]);
    zv[1] = make_float4(aZ[4], aZ[5], aZ[6], aZ[7]);
}

// ---------------------------------------------------------------------------
// Kernel C: mlp+residual (layer 3) then decoder.  Round-5 verbatim.
// ---------------------------------------------------------------------------
__global__ __launch_bounds__(256) void mlp_dec(
    const float* __restrict__ Y, const float* __restrict__ H,
    const float* __restrict__ mlpW, const float* __restrict__ mlp_b,
    const float* __restrict__ dW1, const float* __restrict__ db1,
    const float* __restrict__ dW2, const float* __restrict__ db2,
    float* __restrict__ out)
{
    __shared__ float sMW[32 * 64];
    __shared__ float smb[64];
    __shared__ float sW1t[24 * 65];
    __shared__ float sb1[24];
    __shared__ float sW2[24 * 3];
    __shared__ float sb2v[3];
    for (int idx = threadIdx.x; idx < 32 * 64; idx += 256) sMW[idx] = mlpW[idx];
    for (int idx = threadIdx.x; idx < 64 * 24; idx += 256) {
        int k = idx / 24, t = idx % 24;
        sW1t[t * 65 + k] = dW1[idx];
    }
    if (threadIdx.x < 64) smb[threadIdx.x] = mlp_b[threadIdx.x];
    if (threadIdx.x < 24) sb1[threadIdx.x] = db1[threadIdx.x];
    if (threadIdx.x < 72) sW2[threadIdx.x] = dW2[threadIdx.x];
    if (threadIdx.x < 3)  sb2v[threadIdx.x] = db2[threadIdx.x];
    __syncthreads();

    int gid = blockIdx.x * 256 + threadIdx.x;
    int node = gid >> 2;
    int q = gid & 3;
    if (node >= N_NODES) return;

    float ly[8];
    const float4* yvin = (const float4*)(Y + (size_t)node * 32 + q * 8);
    {
        float4 t0 = yvin[0], t1 = yvin[1];
        ly[0] = leaky(t0.x); ly[1] = leaky(t0.y); ly[2] = leaky(t0.z); ly[3] = leaky(t0.w);
        ly[4] = leaky(t1.x); ly[5] = leaky(t1.y); ly[6] = leaky(t1.z); ly[7] = leaky(t1.w);
    }
    float h[16];
    #pragma unroll
    for (int jj = 0; jj < 16; jj++) h[jj] = smb[q * 16 + jj];
    #pragma unroll
    for (int kk = 0; kk < 8; kk++) {
        #pragma unroll
        for (int ss = 0; ss < 4; ss++) {
            float v = __shfl(ly[kk], ss, 4);
            const float4* w = (const float4*)(sMW + (ss * 8 + kk) * 64 + q * 16);
            float4 a = w[0], b = w[1], c = w[2], d = w[3];
            ACC16(h, v, a, b, c, d)
        }
    }
    const float4* hp = (const float4*)(H + (size_t)node * 64 + q * 16);
    #pragma unroll
    for (int c = 0; c < 4; c++) {
        float4 r = hp[c];
        h[4 * c] += r.x; h[4 * c + 1] += r.y; h[4 * c + 2] += r.z; h[4 * c + 3] += r.w;
    }
    float hid[6];
    #pragma unroll
    for (int t = 0; t < 6; t++) hid[t] = sb1[q * 6 + t];
    #pragma unroll
    for (int kk = 0; kk < 16; kk++) {
        #pragma unroll
        for (int ss = 0; ss < 4; ss++) {
            float v = __shfl(h[kk], ss, 4);
            int k = ss * 16 + kk;
            #pragma unroll
            for (int t = 0; t < 6; t++)
                hid[t] += v * sW1t[(q * 6 + t) * 65 + k];
        }
    }
    float o0 = 0.f, o1 = 0.f, o2 = 0.f;
    #pragma unroll
    for (int t = 0; t < 6; t++) {
        float lt = leaky(hid[t]);
        int tg = q * 6 + t;
        o0 += lt * sW2[tg * 3 + 0];
        o1 += lt * sW2[tg * 3 + 1];
        o2 += lt * sW2[tg * 3 + 2];
    }
    o0 += __shfl_xor(o0, 1, 4); o0 += __shfl_xor(o0, 2, 4);
    o1 += __shfl_xor(o1, 1, 4); o1 += __shfl_xor(o1, 2, 4);
    o2 += __shfl_xor(o2, 1, 4); o2 += __shfl_xor(o2, 2, 4);
    if (q == 0) {
        float* op = out + (size_t)node * 3;
        op[0] = o0 + sb2v[0]; op[1] = o1 + sb2v[1]; op[2] = o2 + sb2v[2];
    }
}

// ---------------------------------------------------------------------------
extern "C" void kernel_launch(void* const* d_in, const int* in_sizes, int n_in,
                              void* d_out, int out_size, void* d_ws, size_t ws_size,
                              hipStream_t stream)
{
    const float* x      = (const float*)d_in[0];
    const int*   esrc   = (const int*)d_in[2];
    const int*   edst   = (const int*)d_in[3];
    const float* ew     = (const float*)d_in[4];
    const float* enc_W1 = (const float*)d_in[5];
    const float* enc_b1 = (const float*)d_in[6];
    const float* enc_W2 = (const float*)d_in[7];
    const float* enc_b2 = (const float*)d_in[8];
    const float* dec_W1 = (const float*)d_in[9];
    const float* dec_b1 = (const float*)d_in[10];
    const float* dec_W2 = (const float*)d_in[11];
    const float* dec_b2 = (const float*)d_in[12];
    const float* ln_g   = (const float*)d_in[13];
    const float* ln_b   = (const float*)d_in[14];
    const float* node_W = (const float*)d_in[15];
    const float* node_b = (const float*)d_in[16];
    const float* edge_W = (const float*)d_in[17];
    const float* edge_b = (const float*)d_in[18];
    const float* mlp_W  = (const float*)d_in[19];
    const float* mlp_b  = (const float*)d_in[20];

    // Workspace: floats H[N*64] | Y[N*32] | Z[N*32] | ep[E int2]
    //            | offs[N+1] | Hg[NBLK*NB2] | T[NB2] | BS[NB2+1]
    float* H  = (float*)d_ws;
    float* Y  = H + (size_t)N_NODES * 64;
    float* Z  = Y + (size_t)N_NODES * 32;
    int2*  ep = (int2*)(Z + (size_t)N_NODES * 32);
    int* offs = (int*)(ep + N_EDGES);
    int* Hg   = offs + N_NODES + 1;
    int* T    = Hg + NBLK * NB2;
    int* BS   = T + NB2;
    // bucket-sorted edge scratch aliases H (dead until enc_ln_gemm)
    int2* sE  = (int2*)H;

    const int pairBlocks    = (NPAIR * 4 + 255) / 256;
    const int node4Blocks   = (N_NODES * 4 + 255) / 256;
    const int gather16Blocks = (N_NODES * 16 + 255) / 256;

    // --- CSR build (zero global atomics) ---
    hist_k<<<NBLK, 256, 0, stream>>>(edst, Hg);
    scan_blocks_k<<<NB2, NBLK, 0, stream>>>(Hg, T);
    scan_T_k<<<1, 256, 0, stream>>>(T, BS);
    scatter_k<<<NBLK, 256, 0, stream>>>(esrc, edst, ew, Hg, BS, sE);
    finalize_k<<<NB2, 256, 0, stream>>>(BS, sE, offs, ep);

    // --- network ---
    enc_ln_gemm<<<pairBlocks, 256, 0, stream>>>(
        x, enc_W1, enc_b1, enc_W2, enc_b2,
        ln_g, ln_b, node_W, node_b, edge_W, edge_b, H, Y, Z);

    for (int l = 0; l < LAYERS - 1; l++) {
        gather_kernel<<<gather16Blocks, 256, 0, stream>>>(offs, ep, Z, Y);
        mlp_ln_gemm<<<node4Blocks, 256, 0, stream>>>(
            Y, H, Z,
            mlp_W + l * 32 * 64, mlp_b + l * 64,
            ln_g + (l + 1) * 64, ln_b + (l + 1) * 64,
            node_W + (l + 1) * 64 * 32, node_b + (l + 1) * 32,
            edge_W + (l + 1) * 64 * 32, edge_b + (l + 1) * 32);
    }
    gather_kernel<<<gather16Blocks, 256, 0, stream>>>(offs, ep, Z, Y);
    mlp_dec<<<node4Blocks, 256, 0, stream>>>(
        Y, H, mlp_W + 3 * 32 * 64, mlp_b + 3 * 64,
        dec_W1, dec_b1, dec_W2, dec_b2, (float*)d_out);
}

// Round 9
// 465.885 us; speedup vs baseline: 1.0898x; 1.0056x over previous
//
#include <hip/hip_runtime.h>

#define N_NODES 100000
#define N_EDGES 1200000
#define LAYERS 4
#define SLOPE 0.01f

#define NPAIR (N_NODES / 2)                 // 50000 (N even)

// two-level zero-atomic counting sort
#define BUCKET_SHIFT 7
#define NB2 ((N_NODES + 127) >> 7)          // 782 buckets of 128 nodes
#define NBLK 128                            // scatter blocks
#define EPB (N_EDGES / NBLK)                // 9375 (exact)

__device__ __forceinline__ float leaky(float v) { return v >= 0.f ? v : SLOPE * v; }

#define ACC16(h, v, a, b, c, d) \
    h[0]  += v * a.x; h[1]  += v * a.y; h[2]  += v * a.z; h[3]  += v * a.w; \
    h[4]  += v * b.x; h[5]  += v * b.y; h[6]  += v * b.z; h[7]  += v * b.w; \
    h[8]  += v * c.x; h[9]  += v * c.y; h[10] += v * c.z; h[11] += v * c.w; \
    h[12] += v * d.x; h[13] += v * d.y; h[14] += v * d.z; h[15] += v * d.w;

#define ACC8(r, v, a, b) \
    r[0] += v * a.x; r[1] += v * a.y; r[2] += v * a.z; r[3] += v * a.w; \
    r[4] += v * b.x; r[5] += v * b.y; r[6] += v * b.z; r[7] += v * b.w;

// ---------------------------------------------------------------------------
// CSR build — zero global atomics (round-4 form, verified).
// ---------------------------------------------------------------------------
__global__ __launch_bounds__(256) void hist_k(
    const int* __restrict__ dst, int* __restrict__ Hg)
{
    __shared__ int lh[NB2];
    for (int i = threadIdx.x; i < NB2; i += 256) lh[i] = 0;
    __syncthreads();
    int blk = blockIdx.x;
    int e1 = blk * EPB + EPB;
    for (int e = blk * EPB + threadIdx.x; e < e1; e += 256)
        atomicAdd(&lh[dst[e] >> BUCKET_SHIFT], 1);
    __syncthreads();
    for (int i = threadIdx.x; i < NB2; i += 256) Hg[blk * NB2 + i] = lh[i];
}

__global__ __launch_bounds__(NBLK) void scan_blocks_k(
    int* __restrict__ Hg, int* __restrict__ T)
{
    __shared__ int s[NBLK];
    int b = blockIdx.x, t = threadIdx.x;
    int v = Hg[t * NB2 + b];
    s[t] = v; __syncthreads();
    for (int off = 1; off < NBLK; off <<= 1) {
        int y = (t >= off) ? s[t - off] : 0;
        __syncthreads();
        s[t] += y;
        __syncthreads();
    }
    Hg[t * NB2 + b] = s[t] - v;
    if (t == NBLK - 1) T[b] = s[t];
}

__global__ __launch_bounds__(256) void scan_T_k(
    const int* __restrict__ T, int* __restrict__ BS)
{
    __shared__ int s[256];
    int t = threadIdx.x;
    int beg = t * 4, end = beg + 4 > NB2 ? NB2 : beg + 4;
    int v[4]; int sum = 0;
    for (int i = beg, u = 0; i < end; i++, u++) { v[u] = sum; sum += T[i]; }
    s[t] = sum; __syncthreads();
    for (int off = 1; off < 256; off <<= 1) {
        int y = (t >= off) ? s[t - off] : 0;
        __syncthreads();
        s[t] += y;
        __syncthreads();
    }
    int excl = s[t] - sum;
    for (int i = beg, u = 0; i < end; i++, u++) BS[i] = excl + v[u];
    if (t == 0) BS[NB2] = N_EDGES;
}

__global__ __launch_bounds__(256) void scatter_k(
    const int* __restrict__ src, const int* __restrict__ dst,
    const float* __restrict__ w, const int* __restrict__ Hg,
    const int* __restrict__ BS, int2* __restrict__ sE)
{
    __shared__ int cur[NB2];
    int blk = blockIdx.x;
    for (int i = threadIdx.x; i < NB2; i += 256)
        cur[i] = BS[i] + Hg[blk * NB2 + i];
    __syncthreads();
    int e1 = blk * EPB + EPB;
    for (int e = blk * EPB + threadIdx.x; e < e1; e += 256) {
        int d = dst[e];
        int p = atomicAdd(&cur[d >> BUCKET_SHIFT], 1);
        sE[p] = make_int2(src[e] | ((d & 127) << 17), __float_as_int(w[e]));
    }
}

__global__ __launch_bounds__(256) void finalize_k(
    const int* __restrict__ BS, const int2* __restrict__ sE,
    int* __restrict__ offs, int2* __restrict__ ep)
{
    __shared__ int cnt[128];
    __shared__ int s[128];
    __shared__ int cur[128];
    int b = blockIdx.x, t = threadIdx.x;
    int s0 = BS[b], s1 = BS[b + 1];
    if (t < 128) cnt[t] = 0;
    __syncthreads();
    for (int i = s0 + t; i < s1; i += 256)
        atomicAdd(&cnt[(sE[i].x >> 17) & 127], 1);
    __syncthreads();
    int v = 0;
    if (t < 128) { v = cnt[t]; s[t] = v; }
    __syncthreads();
    for (int off = 1; off < 128; off <<= 1) {
        int y = (t >= off && t < 128) ? s[t - off] : 0;
        __syncthreads();
        if (t < 128) s[t] += y;
        __syncthreads();
    }
    if (t < 128) {
        int excl = s[t] - v;
        cur[t] = s0 + excl;
        int node = b * 128 + t;
        if (node < N_NODES) offs[node] = s0 + excl;
    }
    if (b == NB2 - 1 && t == 0) offs[N_NODES] = N_EDGES;
    __syncthreads();
    for (int i = s0 + t; i < s1; i += 256) {
        int2 e = sE[i];
        int p = atomicAdd(&cur[(e.x >> 17) & 127], 1);
        ep[p] = make_int2(e.x & 0x1FFFF, e.y);
    }
}

// ---------------------------------------------------------------------------
// Kernel A1: encoder + LN(layer0) -> H.  Split from the old enc_ln_gemm:
// dropping the dual-GEMM weights cuts LDS 58.9 -> 41.3 KB = 3 blocks/CU
// (was 2) to hide LDS latency.  2 nodes/thread, stage-1 fused (round-5 form).
// ---------------------------------------------------------------------------
__global__ __launch_bounds__(256) void enc_k(
    const float* __restrict__ x,
    const float* __restrict__ W1, const float* __restrict__ b1,
    const float* __restrict__ W2, const float* __restrict__ b2,
    const float* __restrict__ ln_g, const float* __restrict__ ln_b,
    float* __restrict__ H)
{
    __shared__ float sW1t[128 * 16];   // [k][i] = W1[i][k]
    __shared__ float sW2[128 * 64];
    __shared__ float sb1[128];
    __shared__ float sb2[64];
    __shared__ float sg[64], sb[64];
    for (int idx = threadIdx.x; idx < 16 * 128; idx += 256) {
        int i = idx / 128, k = idx % 128;
        sW1t[k * 16 + i] = W1[idx];
    }
    for (int idx = threadIdx.x; idx < 128 * 64; idx += 256) sW2[idx] = W2[idx];
    if (threadIdx.x < 128) sb1[threadIdx.x] = b1[threadIdx.x];
    if (threadIdx.x < 64) {
        sb2[threadIdx.x] = b2[threadIdx.x];
        sg[threadIdx.x] = ln_g[threadIdx.x];
        sb[threadIdx.x] = ln_b[threadIdx.x];
    }
    __syncthreads();

    int base = blockIdx.x * 256 + threadIdx.x;
    int pair = base >> 2;
    int q = base & 3;
    if (pair >= NPAIR) return;
    int n0 = pair * 2, n1 = n0 + 1;

    float xi0[16], xi1[16];
    {
        const float4* xv0 = (const float4*)(x + (size_t)n0 * 16);
        const float4* xv1 = (const float4*)(x + (size_t)n1 * 16);
        #pragma unroll
        for (int i = 0; i < 4; i++) {
            float4 t = xv0[i];
            xi0[4 * i] = t.x; xi0[4 * i + 1] = t.y; xi0[4 * i + 2] = t.z; xi0[4 * i + 3] = t.w;
            float4 u = xv1[i];
            xi1[4 * i] = u.x; xi1[4 * i + 1] = u.y; xi1[4 * i + 2] = u.z; xi1[4 * i + 3] = u.w;
        }
    }

    float h0[16], h1[16];
    #pragma unroll
    for (int jj = 0; jj < 16; jj++) { h0[jj] = sb2[q * 16 + jj]; h1[jj] = h0[jj]; }
    #pragma unroll 4
    for (int kk = 0; kk < 32; kk++) {
        int t = kk * 4 + q;
        const float4* wv = (const float4*)(sW1t + t * 16);
        float4 w0 = wv[0], w1 = wv[1], w2 = wv[2], w3 = wv[3];
        float a0 = sb1[t];
        a0 += xi0[0] * w0.x + xi0[1] * w0.y + xi0[2] * w0.z + xi0[3] * w0.w;
        a0 += xi0[4] * w1.x + xi0[5] * w1.y + xi0[6] * w1.z + xi0[7] * w1.w;
        a0 += xi0[8] * w2.x + xi0[9] * w2.y + xi0[10] * w2.z + xi0[11] * w2.w;
        a0 += xi0[12] * w3.x + xi0[13] * w3.y + xi0[14] * w3.z + xi0[15] * w3.w;
        float a1 = sb1[t];
        a1 += xi1[0] * w0.x + xi1[1] * w0.y + xi1[2] * w0.z + xi1[3] * w0.w;
        a1 += xi1[4] * w1.x + xi1[5] * w1.y + xi1[6] * w1.z + xi1[7] * w1.w;
        a1 += xi1[8] * w2.x + xi1[9] * w2.y + xi1[10] * w2.z + xi1[11] * w2.w;
        a1 += xi1[12] * w3.x + xi1[13] * w3.y + xi1[14] * w3.z + xi1[15] * w3.w;
        float hv0 = leaky(a0);
        float hv1 = leaky(a1);
        #pragma unroll
        for (int ss = 0; ss < 4; ss++) {
            float v0 = __shfl(hv0, ss, 4);
            float v1 = __shfl(hv1, ss, 4);
            const float4* w = (const float4*)(sW2 + (kk * 4 + ss) * 64 + q * 16);
            float4 aa = w[0], bb = w[1], cc = w[2], dd = w[3];
            ACC16(h0, v0, aa, bb, cc, dd)
            ACC16(h1, v1, aa, bb, cc, dd)
        }
    }

    // LN over quad (both nodes)
    float s0 = 0.f, e0 = 0.f, s1 = 0.f, e1 = 0.f;
    #pragma unroll
    for (int jj = 0; jj < 16; jj++) {
        s0 += h0[jj]; e0 += h0[jj] * h0[jj];
        s1 += h1[jj]; e1 += h1[jj] * h1[jj];
    }
    s0 += __shfl_xor(s0, 1, 4); s0 += __shfl_xor(s0, 2, 4);
    e0 += __shfl_xor(e0, 1, 4); e0 += __shfl_xor(e0, 2, 4);
    s1 += __shfl_xor(s1, 1, 4); s1 += __shfl_xor(s1, 2, 4);
    e1 += __shfl_xor(e1, 1, 4); e1 += __shfl_xor(e1, 2, 4);
    float mu0 = s0 * (1.f / 64.f);
    float va0 = e0 * (1.f / 64.f) - mu0 * mu0;
    float r0  = rsqrtf(va0 + 1e-5f);
    float mu1 = s1 * (1.f / 64.f);
    float va1 = e1 * (1.f / 64.f) - mu1 * mu1;
    float r1  = rsqrtf(va1 + 1e-5f);

    float4* hs0 = (float4*)(H + (size_t)n0 * 64 + q * 16);
    float4* hs1 = (float4*)(H + (size_t)n1 * 64 + q * 16);
    #pragma unroll
    for (int jj = 0; jj < 16; jj++) {
        float g = sg[q * 16 + jj], bb = sb[q * 16 + jj];
        h0[jj] = (h0[jj] - mu0) * r0 * g + bb;   // hn in place
        h1[jj] = (h1[jj] - mu1) * r1 * g + bb;
    }
    #pragma unroll
    for (int c = 0; c < 4; c++) {
        hs0[c] = make_float4(h0[4 * c], h0[4 * c + 1], h0[4 * c + 2], h0[4 * c + 3]);
        hs1[c] = make_float4(h1[4 * c], h1[4 * c + 1], h1[4 * c + 2], h1[4 * c + 3]);
    }
}

// ---------------------------------------------------------------------------
// Kernel A2: layer-0 dual GEMM.  Reads hn from H, writes Y,Z.  2 nodes/thread
// so each LDS weight read feeds both nodes (same as fused form).  16.5 KB LDS
// -> high occupancy.  Same accumulation order as round-5 -> bit-identical.
// ---------------------------------------------------------------------------
__global__ __launch_bounds__(256) void lg_k(
    const float* __restrict__ H,
    const float* __restrict__ nodeW, const float* __restrict__ node_b,
    const float* __restrict__ edgeW, const float* __restrict__ edge_b,
    float* __restrict__ Y, float* __restrict__ Z)
{
    __shared__ float sNW[64 * 32];
    __shared__ float sEW[64 * 32];
    __shared__ float sby[32];
    for (int idx = threadIdx.x; idx < 64 * 32; idx += 256) {
        sNW[idx] = nodeW[idx];
        sEW[idx] = edgeW[idx];
    }
    if (threadIdx.x < 32) sby[threadIdx.x] = node_b[threadIdx.x] + edge_b[threadIdx.x];
    __syncthreads();

    int base = blockIdx.x * 256 + threadIdx.x;
    int pair = base >> 2;
    int q = base & 3;
    if (pair >= NPAIR) return;
    int n0 = pair * 2, n1 = n0 + 1;

    float h0[16], h1[16];
    {
        const float4* hp0 = (const float4*)(H + (size_t)n0 * 64 + q * 16);
        const float4* hp1 = (const float4*)(H + (size_t)n1 * 64 + q * 16);
        #pragma unroll
        for (int c = 0; c < 4; c++) {
            float4 r0 = hp0[c];
            h0[4 * c] = r0.x; h0[4 * c + 1] = r0.y; h0[4 * c + 2] = r0.z; h0[4 * c + 3] = r0.w;
            float4 r1 = hp1[c];
            h1[4 * c] = r1.x; h1[4 * c + 1] = r1.y; h1[4 * c + 2] = r1.z; h1[4 * c + 3] = r1.w;
        }
    }

    float aY0[8], aZ0[8], aY1[8], aZ1[8];
    #pragma unroll
    for (int jj = 0; jj < 8; jj++) {
        aY0[jj] = sby[q * 8 + jj]; aY1[jj] = aY0[jj];
        aZ0[jj] = 0.f; aZ1[jj] = 0.f;
    }
    #pragma unroll
    for (int kk = 0; kk < 16; kk++) {
        #pragma unroll
        for (int ss = 0; ss < 4; ss++) {
            float v0 = __shfl(h0[kk], ss, 4);
            float v1 = __shfl(h1[kk], ss, 4);
            int k = ss * 16 + kk;
            const float4* nw = (const float4*)(sNW + k * 32 + q * 8);
            const float4* ew = (const float4*)(sEW + k * 32 + q * 8);
            float4 a = nw[0], b = nw[1], c = ew[0], d = ew[1];
            ACC8(aY0, v0, a, b)
            ACC8(aZ0, v0, c, d)
            ACC8(aY1, v1, a, b)
            ACC8(aZ1, v1, c, d)
        }
    }
    float4* yv0 = (float4*)(Y + (size_t)n0 * 32 + q * 8);
    float4* zv0 = (float4*)(Z + (size_t)n0 * 32 + q * 8);
    float4* yv1 = (float4*)(Y + (size_t)n1 * 32 + q * 8);
    float4* zv1 = (float4*)(Z + (size_t)n1 * 32 + q * 8);
    yv0[0] = make_float4(aY0[0], aY0[1], aY0[2], aY0[3]);
    yv0[1] = make_float4(aY0[4], aY0[5], aY0[6], aY0[7]);
    zv0[0] = make_float4(aZ0[0], aZ0[1], aZ0[2], aZ0[3]);
    zv0[1] = make_float4(aZ0[4], aZ0[5], aZ0[6], aZ0[7]);
    yv1[0] = make_float4(aY1[0], aY1[1], aY1[2], aY1[3]);
    yv1[1] = make_float4(aY1[4], aY1[5], aY1[6], aY1[7]);
    zv1[0] = make_float4(aZ1[0], aZ1[1], aZ1[2], aZ1[3]);
    zv1[1] = make_float4(aZ1[4], aZ1[5], aZ1[6], aZ1[7]);
}

// ---------------------------------------------------------------------------
// Gather: Y[n] += sum_e w_e * Z[src_e].  Round-5 form (8 lanes/node,
// unroll-4): best measured; 16-lane split (round 8) was neutral-negative.
// ---------------------------------------------------------------------------
__global__ __launch_bounds__(256) void gather_kernel(
    const int* __restrict__ offs, const int2* __restrict__ ep,
    const float* __restrict__ Z, float* __restrict__ Y)
{
    int gid = blockIdx.x * 256 + threadIdx.x;
    int node = gid >> 3;
    int lane = gid & 7;
    if (node >= N_NODES) return;
    int p0 = offs[node], p1 = offs[node + 1];
    float4 acc = make_float4(0.f, 0.f, 0.f, 0.f);
    const float4* Zv = (const float4*)Z;
    int p = p0;
    for (; p + 4 <= p1; p += 4) {
        int2 ea = ep[p];
        int2 eb = ep[p + 1];
        int2 ec = ep[p + 2];
        int2 ed = ep[p + 3];
        float4 za = Zv[(size_t)ea.x * 8 + lane];
        float4 zb = Zv[(size_t)eb.x * 8 + lane];
        float4 zc = Zv[(size_t)ec.x * 8 + lane];
        float4 zd = Zv[(size_t)ed.x * 8 + lane];
        float wa = __int_as_float(ea.y);
        float wb = __int_as_float(eb.y);
        float wc = __int_as_float(ec.y);
        float wd = __int_as_float(ed.y);
        acc.x += wa * za.x + wb * zb.x + wc * zc.x + wd * zd.x;
        acc.y += wa * za.y + wb * zb.y + wc * zc.y + wd * zd.y;
        acc.z += wa * za.z + wb * zb.z + wc * zc.z + wd * zd.z;
        acc.w += wa * za.w + wb * zb.w + wc * zc.w + wd * zd.w;
    }
    for (; p < p1; p++) {
        int2 ea = ep[p];
        float wa = __int_as_float(ea.y);
        float4 za = Zv[(size_t)ea.x * 8 + lane];
        acc.x += wa * za.x; acc.y += wa * za.y;
        acc.z += wa * za.z; acc.w += wa * za.w;
    }
    float4* yp = (float4*)(Y + (size_t)node * 32) + lane;
    float4 y = *yp;
    y.x += acc.x; y.y += acc.y; y.z += acc.z; y.w += acc.w;
    *yp = y;
}

// ---------------------------------------------------------------------------
// Kernel B: mlp+residual (layer l) then LN + dual GEMM (layer l+1).
// Round-5 verbatim (at its LDS-traffic floor).
// ---------------------------------------------------------------------------
__global__ __launch_bounds__(256) void mlp_ln_gemm(
    float* __restrict__ Yio, float* __restrict__ H, float* __restrict__ Z,
    const float* __restrict__ mlpW, const float* __restrict__ mlp_b,
    const float* __restrict__ ln_g, const float* __restrict__ ln_b,
    const float* __restrict__ nodeW, const float* __restrict__ node_b,
    const float* __restrict__ edgeW, const float* __restrict__ edge_b)
{
    __shared__ float sMW[32 * 64];
    __shared__ float sNW[64 * 32];
    __shared__ float sEW[64 * 32];
    __shared__ float smb[64], sg[64], sb[64], sby[32];
    for (int idx = threadIdx.x; idx < 32 * 64; idx += 256) sMW[idx] = mlpW[idx];
    for (int idx = threadIdx.x; idx < 64 * 32; idx += 256) {
        sNW[idx] = nodeW[idx];
        sEW[idx] = edgeW[idx];
    }
    if (threadIdx.x < 64) {
        smb[threadIdx.x] = mlp_b[threadIdx.x];
        sg[threadIdx.x] = ln_g[threadIdx.x];
        sb[threadIdx.x] = ln_b[threadIdx.x];
    }
    if (threadIdx.x < 32) sby[threadIdx.x] = node_b[threadIdx.x] + edge_b[threadIdx.x];
    __syncthreads();

    int gid = blockIdx.x * 256 + threadIdx.x;
    int node = gid >> 2;
    int q = gid & 3;
    if (node >= N_NODES) return;

    float ly[8];
    const float4* yvin = (const float4*)(Yio + (size_t)node * 32 + q * 8);
    {
        float4 t0 = yvin[0], t1 = yvin[1];
        ly[0] = leaky(t0.x); ly[1] = leaky(t0.y); ly[2] = leaky(t0.z); ly[3] = leaky(t0.w);
        ly[4] = leaky(t1.x); ly[5] = leaky(t1.y); ly[6] = leaky(t1.z); ly[7] = leaky(t1.w);
    }
    float h[16];
    #pragma unroll
    for (int jj = 0; jj < 16; jj++) h[jj] = smb[q * 16 + jj];
    #pragma unroll
    for (int kk = 0; kk < 8; kk++) {
        #pragma unroll
        for (int ss = 0; ss < 4; ss++) {
            float v = __shfl(ly[kk], ss, 4);
            const float4* w = (const float4*)(sMW + (ss * 8 + kk) * 64 + q * 16);
            float4 a = w[0], b = w[1], c = w[2], d = w[3];
            ACC16(h, v, a, b, c, d)
        }
    }
    float4* hp = (float4*)(H + (size_t)node * 64 + q * 16);
    #pragma unroll
    for (int c = 0; c < 4; c++) {
        float4 r = hp[c];
        h[4 * c] += r.x; h[4 * c + 1] += r.y; h[4 * c + 2] += r.z; h[4 * c + 3] += r.w;
    }
    float s = 0.f, s2 = 0.f;
    #pragma unroll
    for (int jj = 0; jj < 16; jj++) { s += h[jj]; s2 += h[jj] * h[jj]; }
    s  += __shfl_xor(s, 1, 4);  s  += __shfl_xor(s, 2, 4);
    s2 += __shfl_xor(s2, 1, 4); s2 += __shfl_xor(s2, 2, 4);
    float mu  = s * (1.f / 64.f);
    float var = s2 * (1.f / 64.f) - mu * mu;
    float rs  = rsqrtf(var + 1e-5f);

    float hn[16];
    #pragma unroll
    for (int jj = 0; jj < 16; jj++)
        hn[jj] = (h[jj] - mu) * rs * sg[q * 16 + jj] + sb[q * 16 + jj];
    #pragma unroll
    for (int c = 0; c < 4; c++)
        hp[c] = make_float4(hn[4 * c], hn[4 * c + 1], hn[4 * c + 2], hn[4 * c + 3]);

    float aY[8], aZ[8];
    #pragma unroll
    for (int jj = 0; jj < 8; jj++) { aY[jj] = sby[q * 8 + jj]; aZ[jj] = 0.f; }
    #pragma unroll
    for (int kk = 0; kk < 16; kk++) {
        #pragma unroll
        for (int ss = 0; ss < 4; ss++) {
            float v = __shfl(hn[kk], ss, 4);
            int k = ss * 16 + kk;
            const float4* nw = (const float4*)(sNW + k * 32 + q * 8);
            const float4* ew = (const float4*)(sEW + k * 32 + q * 8);
            float4 a = nw[0], b = nw[1], c = ew[0], d = ew[1];
            ACC8(aY, v, a, b)
            ACC8(aZ, v, c, d)
        }
    }
    float4* yo = (float4*)(Yio + (size_t)node * 32 + q * 8);
    float4* zv = (float4*)(Z + (size_t)node * 32 + q * 8);
    yo[0] = make_float4(aY[0], aY[1], aY[2], aY[3]);
    yo[1] = make_float4(aY[4], aY[5], aY[6], aY[7]);
    zv[0] = make_float4(aZ[0], aZ[1], aZ[2], aZ[3]);
    zv[1] = make_float4(aZ[4], aZ[5], aZ[6], aZ[7]);
}

// ---------------------------------------------------------------------------
// Kernel C: mlp+residual (layer 3) then decoder.  Round-5 verbatim.
// ---------------------------------------------------------------------------
__global__ __launch_bounds__(256) void mlp_dec(
    const float* __restrict__ Y, const float* __restrict__ H,
    const float* __restrict__ mlpW, const float* __restrict__ mlp_b,
    const float* __restrict__ dW1, const float* __restrict__ db1,
    const float* __restrict__ dW2, const float* __restrict__ db2,
    float* __restrict__ out)
{
    __shared__ float sMW[32 * 64];
    __shared__ float smb[64];
    __shared__ float sW1t[24 * 65];
    __shared__ float sb1[24];
    __shared__ float sW2[24 * 3];
    __shared__ float sb2v[3];
    for (int idx = threadIdx.x; idx < 32 * 64; idx += 256) sMW[idx] = mlpW[idx];
    for (int idx = threadIdx.x; idx < 64 * 24; idx += 256) {
        int k = idx / 24, t = idx % 24;
        sW1t[t * 65 + k] = dW1[idx];
    }
    if (threadIdx.x < 64) smb[threadIdx.x] = mlp_b[threadIdx.x];
    if (threadIdx.x < 24) sb1[threadIdx.x] = db1[threadIdx.x];
    if (threadIdx.x < 72) sW2[threadIdx.x] = dW2[threadIdx.x];
    if (threadIdx.x < 3)  sb2v[threadIdx.x] = db2[threadIdx.x];
    __syncthreads();

    int gid = blockIdx.x * 256 + threadIdx.x;
    int node = gid >> 2;
    int q = gid & 3;
    if (node >= N_NODES) return;

    float ly[8];
    const float4* yvin = (const float4*)(Y + (size_t)node * 32 + q * 8);
    {
        float4 t0 = yvin[0], t1 = yvin[1];
        ly[0] = leaky(t0.x); ly[1] = leaky(t0.y); ly[2] = leaky(t0.z); ly[3] = leaky(t0.w);
        ly[4] = leaky(t1.x); ly[5] = leaky(t1.y); ly[6] = leaky(t1.z); ly[7] = leaky(t1.w);
    }
    float h[16];
    #pragma unroll
    for (int jj = 0; jj < 16; jj++) h[jj] = smb[q * 16 + jj];
    #pragma unroll
    for (int kk = 0; kk < 8; kk++) {
        #pragma unroll
        for (int ss = 0; ss < 4; ss++) {
            float v = __shfl(ly[kk], ss, 4);
            const float4* w = (const float4*)(sMW + (ss * 8 + kk) * 64 + q * 16);
            float4 a = w[0], b = w[1], c = w[2], d = w[3];
            ACC16(h, v, a, b, c, d)
        }
    }
    const float4* hp = (const float4*)(H + (size_t)node * 64 + q * 16);
    #pragma unroll
    for (int c = 0; c < 4; c++) {
        float4 r = hp[c];
        h[4 * c] += r.x; h[4 * c + 1] += r.y; h[4 * c + 2] += r.z; h[4 * c + 3] += r.w;
    }
    float hid[6];
    #pragma unroll
    for (int t = 0; t < 6; t++) hid[t] = sb1[q * 6 + t];
    #pragma unroll
    for (int kk = 0; kk < 16; kk++) {
        #pragma unroll
        for (int ss = 0; ss < 4; ss++) {
            float v = __shfl(h[kk], ss, 4);
            int k = ss * 16 + kk;
            #pragma unroll
            for (int t = 0; t < 6; t++)
                hid[t] += v * sW1t[(q * 6 + t) * 65 + k];
        }
    }
    float o0 = 0.f, o1 = 0.f, o2 = 0.f;
    #pragma unroll
    for (int t = 0; t < 6; t++) {
        float lt = leaky(hid[t]);
        int tg = q * 6 + t;
        o0 += lt * sW2[tg * 3 + 0];
        o1 += lt * sW2[tg * 3 + 1];
        o2 += lt * sW2[tg * 3 + 2];
    }
    o0 += __shfl_xor(o0, 1, 4); o0 += __shfl_xor(o0, 2, 4);
    o1 += __shfl_xor(o1, 1, 4); o1 += __shfl_xor(o1, 2, 4);
    o2 += __shfl_xor(o2, 1, 4); o2 += __shfl_xor(o2, 2, 4);
    if (q == 0) {
        float* op = out + (size_t)node * 3;
        op[0] = o0 + sb2v[0]; op[1] = o1 + sb2v[1]; op[2] = o2 + sb2v[2];
    }
}

// ---------------------------------------------------------------------------
extern "C" void kernel_launch(void* const* d_in, const int* in_sizes, int n_in,
                              void* d_out, int out_size, void* d_ws, size_t ws_size,
                              hipStream_t stream)
{
    const float* x      = (const float*)d_in[0];
    const int*   esrc   = (const int*)d_in[2];
    const int*   edst   = (const int*)d_in[3];
    const float* ew     = (const float*)d_in[4];
    const float* enc_W1 = (const float*)d_in[5];
    const float* enc_b1 = (const float*)d_in[6];
    const float* enc_W2 = (const float*)d_in[7];
    const float* enc_b2 = (const float*)d_in[8];
    const float* dec_W1 = (const float*)d_in[9];
    const float* dec_b1 = (const float*)d_in[10];
    const float* dec_W2 = (const float*)d_in[11];
    const float* dec_b2 = (const float*)d_in[12];
    const float* ln_g   = (const float*)d_in[13];
    const float* ln_b   = (const float*)d_in[14];
    const float* node_W = (const float*)d_in[15];
    const float* node_b = (const float*)d_in[16];
    const float* edge_W = (const float*)d_in[17];
    const float* edge_b = (const float*)d_in[18];
    const float* mlp_W  = (const float*)d_in[19];
    const float* mlp_b  = (const float*)d_in[20];

    // Workspace: floats H[N*64] | Y[N*32] | Z[N*32] | ep[E int2]
    //            | offs[N+1] | Hg[NBLK*NB2] | T[NB2] | BS[NB2+1]
    float* H  = (float*)d_ws;
    float* Y  = H + (size_t)N_NODES * 64;
    float* Z  = Y + (size_t)N_NODES * 32;
    int2*  ep = (int2*)(Z + (size_t)N_NODES * 32);
    int* offs = (int*)(ep + N_EDGES);
    int* Hg   = offs + N_NODES + 1;
    int* T    = Hg + NBLK * NB2;
    int* BS   = T + NB2;
    // bucket-sorted edge scratch aliases H (dead until enc_k)
    int2* sE  = (int2*)H;

    const int pairBlocks   = (NPAIR * 4 + 255) / 256;
    const int node4Blocks  = (N_NODES * 4 + 255) / 256;
    const int gatherBlocks = (N_NODES * 8 + 255) / 256;

    // --- CSR build (zero global atomics) ---
    hist_k<<<NBLK, 256, 0, stream>>>(edst, Hg);
    scan_blocks_k<<<NB2, NBLK, 0, stream>>>(Hg, T);
    scan_T_k<<<1, 256, 0, stream>>>(T, BS);
    scatter_k<<<NBLK, 256, 0, stream>>>(esrc, edst, ew, Hg, BS, sE);
    finalize_k<<<NB2, 256, 0, stream>>>(BS, sE, offs, ep);

    // --- network ---
    enc_k<<<pairBlocks, 256, 0, stream>>>(
        x, enc_W1, enc_b1, enc_W2, enc_b2, ln_g, ln_b, H);
    lg_k<<<pairBlocks, 256, 0, stream>>>(
        H, node_W, node_b, edge_W, edge_b, Y, Z);

    for (int l = 0; l < LAYERS - 1; l++) {
        gather_kernel<<<gatherBlocks, 256, 0, stream>>>(offs, ep, Z, Y);
        mlp_ln_gemm<<<node4Blocks, 256, 0, stream>>>(
            Y, H, Z,
            mlp_W + l * 32 * 64, mlp_b + l * 64,
            ln_g + (l + 1) * 64, ln_b + (l + 1) * 64,
            node_W + (l + 1) * 64 * 32, node_b + (l + 1) * 32,
            edge_W + (l + 1) * 64 * 32, edge_b + (l + 1) * 32);
    }
    gather_kernel<<<gatherBlocks, 256, 0, stream>>>(offs, ep, Z, Y);
    mlp_dec<<<node4Blocks, 256, 0, stream>>>(
        Y, H, mlp_W + 3 * 32 * 64, mlp_b + 3 * 64,
        dec_W1, dec_b1, dec_W2, dec_b2, (float*)d_out);
}